// Round 5
// baseline (257.063 us; speedup 1.0000x reference)
//
#include <hip/hip_runtime.h>

// ExampleModelSISO: out = x * exclusive_cumsum(x, axis=time)
// x: [B=8, T=4096, D=1024] float32, out same shape.
//
// R8: 2-kernel chunked scan (R7 structure) at C=128.
// Evidence: traffic is compulsory (R5: FETCH 135 MB + WRITE 139 MB; x
// re-read fully L3-absorbed by NT out-stores). ~171 µs of the timed window
// is harness fills/overhead; kernel-side ~78 µs vs ~50 µs floor. R8 attacks
// latency-hiding: C=64 gave only 2 blocks/CU (8 waves/CU) — thin for two
// ~25 µs kernels dominated by ramp/tail. C=128 -> 1024 blocks, 4/CU,
// 16 waves/CU.
//  - k3 computes its own chunk prefix from the 4 MB L2/L3-resident part
//    array (<=127 coalesced vf4 loads/thread, 8-chain tree).
//  - out stores nontemporal so x stays L3-resident between kernels.

typedef float vf4 __attribute__((ext_vector_type(4)));

constexpr int B = 8;
constexpr int T = 4096;
constexpr int D = 1024;
constexpr int C = 128;       // chunks along T
constexpr int L = T / C;     // 32 timesteps per chunk
constexpr int THREADS = 256; // 256 threads * float4 = 1024 = D

// part layout: part[(c*B + b)*D + d]  (coalesced in d for fixed (c,b))
// size = C*B*D*4 = 4 MiB of workspace.

// Kernel 1: per-chunk column sums. Block = one (b, chunk).
__global__ __launch_bounds__(THREADS)
void partial_sums(const float* __restrict__ x, float* __restrict__ part) {
    const int bc = blockIdx.x;
    const int b = bc / C;
    const int c = bc % C;
    const int d4 = threadIdx.x * 4;

    const float* px = x + ((size_t)(b * T + c * L)) * D + d4;
    vf4 acc = (vf4)(0.f);
#pragma unroll 16
    for (int t = 0; t < L; ++t)
        acc += *(const vf4*)(px + (size_t)t * D);
    *(vf4*)(part + ((size_t)c * B + b) * D + d4) = acc;
}

// Kernel 2: per-block chunk prefix from partials, then within-chunk
// exclusive scan + multiply, nontemporal store.
__global__ __launch_bounds__(THREADS)
void scan_mul(const float* __restrict__ x, const float* __restrict__ part,
              float* __restrict__ out) {
    const int bc = blockIdx.x;
    const int b = bc / C;
    const int c = bc % C;
    const int d4 = threadIdx.x * 4;

    // ---- chunk prefix: sum part[p][b][d4..] over p < c, 8 independent chains
    vf4 s0 = (vf4)(0.f), s1 = (vf4)(0.f), s2 = (vf4)(0.f), s3 = (vf4)(0.f);
    vf4 s4 = (vf4)(0.f), s5 = (vf4)(0.f), s6 = (vf4)(0.f), s7 = (vf4)(0.f);
    {
        const float* pp = part + (size_t)b * D + d4;
        const size_t stride = (size_t)B * D;
        int p = 0;
        for (; p + 8 <= c; p += 8) {
            s0 += *(const vf4*)(pp + (size_t)(p + 0) * stride);
            s1 += *(const vf4*)(pp + (size_t)(p + 1) * stride);
            s2 += *(const vf4*)(pp + (size_t)(p + 2) * stride);
            s3 += *(const vf4*)(pp + (size_t)(p + 3) * stride);
            s4 += *(const vf4*)(pp + (size_t)(p + 4) * stride);
            s5 += *(const vf4*)(pp + (size_t)(p + 5) * stride);
            s6 += *(const vf4*)(pp + (size_t)(p + 6) * stride);
            s7 += *(const vf4*)(pp + (size_t)(p + 7) * stride);
        }
        for (; p < c; ++p)
            s0 += *(const vf4*)(pp + (size_t)p * stride);
    }
    vf4 s = ((s0 + s1) + (s2 + s3)) + ((s4 + s5) + (s6 + s7));

    // ---- within-chunk exclusive scan + multiply
    const size_t base = ((size_t)(b * T + c * L)) * D + d4;
#pragma unroll 8
    for (int t = 0; t < L; ++t) {
        vf4 v = *(const vf4*)(x + base + (size_t)t * D);
        vf4 o = v * s;
        s += v;
        __builtin_nontemporal_store(o, (vf4*)(out + base + (size_t)t * D));
    }
}

extern "C" void kernel_launch(void* const* d_in, const int* in_sizes, int n_in,
                              void* d_out, int out_size, void* d_ws, size_t ws_size,
                              hipStream_t stream) {
    const float* x = (const float*)d_in[0];
    float* out = (float*)d_out;
    float* part = (float*)d_ws; // C*B*D*4 = 4 MiB of scratch

    partial_sums<<<B * C, THREADS, 0, stream>>>(x, part);
    scan_mul<<<B * C, THREADS, 0, stream>>>(x, part, out);
}

// Round 6
// 254.409 us; speedup vs baseline: 1.0104x; 1.0104x over previous
//
#include <hip/hip_runtime.h>

// ExampleModelSISO: out = x * exclusive_cumsum(x, axis=time)
// x: [B=8, T=4096, D=1024] float32, out same shape.
//
// R9: hybrid 2-kernel chunked scan.
// R8 post-mortem: C=128 for BOTH kernels regressed (k3's prefix traffic
// quadrupled); C=64 (R7, 249.1 µs) is the proven k3 shape. R9 splits the
// knobs:
//  - k1: fine partials at C1=128 -> 1024 blocks, 4 blocks/CU (better ramp
//    for the pure-read kernel).
//  - k3: C3=64 chunks (512 blocks, 64-step streaming loop); chunk prefix =
//    sum of fine partials p < 2c (<=126 coalesced vf4 loads from the 4 MiB
//    L2/L3-resident array, 8-chain tree).
//  - out stores nontemporal so x stays L3-resident for k3's re-read
//    (proven by R5: FETCH 135 MB total — re-read fully L3-absorbed).

typedef float vf4 __attribute__((ext_vector_type(4)));

constexpr int B = 8;
constexpr int T = 4096;
constexpr int D = 1024;
constexpr int C1 = 128;      // fine chunks (k1)
constexpr int L1 = T / C1;   // 32 timesteps per fine chunk
constexpr int C3 = 64;       // coarse chunks (k3)
constexpr int L3 = T / C3;   // 64 timesteps per coarse chunk
constexpr int THREADS = 256; // 256 threads * float4 = 1024 = D

// part layout: part[(p*B + b)*D + d], p in [0,C1)  — 4 MiB workspace.

// Kernel 1: fine per-chunk column sums. Block = one (b, fine chunk).
__global__ __launch_bounds__(THREADS)
void partial_sums(const float* __restrict__ x, float* __restrict__ part) {
    const int bc = blockIdx.x;
    const int b = bc / C1;
    const int p = bc % C1;
    const int d4 = threadIdx.x * 4;

    const float* px = x + ((size_t)(b * T + p * L1)) * D + d4;
    vf4 acc = (vf4)(0.f);
#pragma unroll 16
    for (int t = 0; t < L1; ++t)
        acc += *(const vf4*)(px + (size_t)t * D);
    *(vf4*)(part + ((size_t)p * B + b) * D + d4) = acc;
}

// Kernel 2: per-block coarse-chunk prefix from fine partials, then
// within-chunk exclusive scan + multiply, nontemporal store.
__global__ __launch_bounds__(THREADS)
void scan_mul(const float* __restrict__ x, const float* __restrict__ part,
              float* __restrict__ out) {
    const int bc = blockIdx.x;
    const int b = bc / C3;
    const int c = bc % C3;
    const int d4 = threadIdx.x * 4;

    // ---- chunk prefix: sum fine partials p < 2c, 8 independent chains
    const int pc = 2 * c;
    vf4 s0 = (vf4)(0.f), s1 = (vf4)(0.f), s2 = (vf4)(0.f), s3 = (vf4)(0.f);
    vf4 s4 = (vf4)(0.f), s5 = (vf4)(0.f), s6 = (vf4)(0.f), s7 = (vf4)(0.f);
    {
        const float* pp = part + (size_t)b * D + d4;
        const size_t stride = (size_t)B * D;
        int p = 0;
        for (; p + 8 <= pc; p += 8) {
            s0 += *(const vf4*)(pp + (size_t)(p + 0) * stride);
            s1 += *(const vf4*)(pp + (size_t)(p + 1) * stride);
            s2 += *(const vf4*)(pp + (size_t)(p + 2) * stride);
            s3 += *(const vf4*)(pp + (size_t)(p + 3) * stride);
            s4 += *(const vf4*)(pp + (size_t)(p + 4) * stride);
            s5 += *(const vf4*)(pp + (size_t)(p + 5) * stride);
            s6 += *(const vf4*)(pp + (size_t)(p + 6) * stride);
            s7 += *(const vf4*)(pp + (size_t)(p + 7) * stride);
        }
        for (; p < pc; ++p)
            s0 += *(const vf4*)(pp + (size_t)p * stride);
    }
    vf4 s = ((s0 + s1) + (s2 + s3)) + ((s4 + s5) + (s6 + s7));

    // ---- within-chunk exclusive scan + multiply
    const size_t base = ((size_t)(b * T + c * L3)) * D + d4;
#pragma unroll 8
    for (int t = 0; t < L3; ++t) {
        vf4 v = *(const vf4*)(x + base + (size_t)t * D);
        vf4 o = v * s;
        s += v;
        __builtin_nontemporal_store(o, (vf4*)(out + base + (size_t)t * D));
    }
}

extern "C" void kernel_launch(void* const* d_in, const int* in_sizes, int n_in,
                              void* d_out, int out_size, void* d_ws, size_t ws_size,
                              hipStream_t stream) {
    const float* x = (const float*)d_in[0];
    float* out = (float*)d_out;
    float* part = (float*)d_ws; // C1*B*D*4 = 4 MiB of scratch

    partial_sums<<<B * C1, THREADS, 0, stream>>>(x, part);
    scan_mul<<<B * C3, THREADS, 0, stream>>>(x, part, out);
}

// Round 7
// 248.702 us; speedup vs baseline: 1.0336x; 1.0229x over previous
//
#include <hip/hip_runtime.h>

// ExampleModelSISO: out = x * exclusive_cumsum(x, axis=time)
// x: [B=8, T=4096, D=1024] float32, out same shape.
//
// R10 = R7 restored (session best, 249.1 µs). 2-kernel chunked scan, C=64.
// Session evidence summary:
//  - HBM traffic is compulsory: FETCH 135 MB + WRITE 139 MB (R5 coop run);
//    k3's x re-read is fully L3-absorbed thanks to NT out-stores.
//  - Single-pass lookback (R4): agent-scope atomic polls cross the XCD
//    coherence point (~900 cy each) -> livelock. Rejected.
//  - Cooperative grid.sync (R5): ~100 µs/barrier on 1024 blocks across 8
//    non-coherent XCDs. Rejected.
//  - Shape scans (R6/R8/R9): C3=64 + fused coarse prefix is the family
//    optimum; C=128 variants regress via prefix-read amplification.
//  - ~160 µs of the timed window is harness re-poison fill (2 x 512 MiB
//    fillBufferAligned @ ~79 µs, 85% of HBM peak). Kernel-side ~78 µs vs
//    ~50 µs ideal floor; the residual is launch gap + ramp of two short
//    dispatches — all structural alternatives measured slower.

typedef float vf4 __attribute__((ext_vector_type(4)));

constexpr int B = 8;
constexpr int T = 4096;
constexpr int D = 1024;
constexpr int C = 64;        // chunks along T
constexpr int L = T / C;     // 64 timesteps per chunk
constexpr int THREADS = 256; // 256 threads * float4 = 1024 = D

// part layout: part[(c*B + b)*D + d]  (coalesced in d for fixed (c,b))
// size = C*B*D*4 = 2 MiB of workspace.

// Kernel 1: per-chunk column sums. Block = one (b, chunk).
__global__ __launch_bounds__(THREADS)
void partial_sums(const float* __restrict__ x, float* __restrict__ part) {
    const int bc = blockIdx.x;
    const int b = bc / C;
    const int c = bc % C;
    const int d4 = threadIdx.x * 4;

    const float* px = x + ((size_t)(b * T + c * L)) * D + d4;
    vf4 acc = (vf4)(0.f);
#pragma unroll 16
    for (int t = 0; t < L; ++t)
        acc += *(const vf4*)(px + (size_t)t * D);
    *(vf4*)(part + ((size_t)c * B + b) * D + d4) = acc;
}

// Kernel 2: per-block chunk prefix from partials, then within-chunk
// exclusive scan + multiply, nontemporal store.
__global__ __launch_bounds__(THREADS)
void scan_mul(const float* __restrict__ x, const float* __restrict__ part,
              float* __restrict__ out) {
    const int bc = blockIdx.x;
    const int b = bc / C;
    const int c = bc % C;
    const int d4 = threadIdx.x * 4;

    // ---- chunk prefix: sum part[p][b][d4] over p < c, 4 independent chains
    vf4 s0 = (vf4)(0.f), s1 = (vf4)(0.f), s2 = (vf4)(0.f), s3 = (vf4)(0.f);
    {
        const float* pp = part + (size_t)b * D + d4;
        int p = 0;
        for (; p + 4 <= c; p += 4) {
            s0 += *(const vf4*)(pp + (size_t)(p + 0) * B * D);
            s1 += *(const vf4*)(pp + (size_t)(p + 1) * B * D);
            s2 += *(const vf4*)(pp + (size_t)(p + 2) * B * D);
            s3 += *(const vf4*)(pp + (size_t)(p + 3) * B * D);
        }
        for (; p < c; ++p)
            s0 += *(const vf4*)(pp + (size_t)p * B * D);
    }
    vf4 s = (s0 + s1) + (s2 + s3);

    // ---- within-chunk exclusive scan + multiply
    const size_t base = ((size_t)(b * T + c * L)) * D + d4;
#pragma unroll 8
    for (int t = 0; t < L; ++t) {
        vf4 v = *(const vf4*)(x + base + (size_t)t * D);
        vf4 o = v * s;
        s += v;
        __builtin_nontemporal_store(o, (vf4*)(out + base + (size_t)t * D));
    }
}

extern "C" void kernel_launch(void* const* d_in, const int* in_sizes, int n_in,
                              void* d_out, int out_size, void* d_ws, size_t ws_size,
                              hipStream_t stream) {
    const float* x = (const float*)d_in[0];
    float* out = (float*)d_out;
    float* part = (float*)d_ws; // C*B*D*4 = 2 MiB of scratch

    partial_sums<<<B * C, THREADS, 0, stream>>>(x, part);
    scan_mul<<<B * C, THREADS, 0, stream>>>(x, part, out);
}